// Round 1
// baseline (1746.829 us; speedup 1.0000x reference)
//
#include <hip/hip_runtime.h>

#define N1 30
#define N2 60
#define T_STEPS 1024
#define BATCH 2048

typedef _Float16 h2_t __attribute__((ext_vector_type(2)));

// tanh(x) = 1 - 2/(exp(2x)+1)  -- stable for large |x| (-> +-1), no NaN.
__device__ __forceinline__ float fast_tanh(float x) {
  float e = __expf(2.0f * x);                    // v_mul + v_exp_f32
  float r = __builtin_amdgcn_rcpf(e + 1.0f);     // v_rcp_f32
  return fmaf(-2.0f, r, 1.0f);
}

// acc += a.x*b.x + a.y*b.y   (f16 inputs, fp32 accumulate, full-rate v_dot2_f32_f16)
__device__ __forceinline__ float dot2(unsigned a, unsigned b, float acc) {
#if __has_builtin(__builtin_amdgcn_fdot2)
  return __builtin_amdgcn_fdot2(__builtin_bit_cast(h2_t, a),
                                __builtin_bit_cast(h2_t, b), acc, false);
#else
  // correctness fallback (slower): unpack and fma in fp32
  h2_t ha = __builtin_bit_cast(h2_t, a);
  h2_t hb = __builtin_bit_cast(h2_t, b);
  return fmaf((float)ha.x, (float)hb.x, fmaf((float)ha.y, (float)hb.y, acc));
#endif
}

// Pack two fp32 into 2xf16 with round-to-nearest-even (v_cvt_f16_f32 x2 + pack).
__device__ __forceinline__ unsigned pack_f16(float lo, float hi) {
  h2_t p;
  p.x = (_Float16)lo;
  p.y = (_Float16)hi;
  return __builtin_bit_cast(unsigned, p);
}

// Broadcast lane l's 32-bit value (a packed f16 pair) to all lanes.
__device__ __forceinline__ unsigned lane_bcast_u(unsigned v, int l) {
  return (unsigned)__builtin_amdgcn_readlane((int)v, l);
}

// __launch_bounds__(256, 2): 2 waves/EU -> VGPR cap 256. Grid is 2048 waves
// (2 waves/SIMD) regardless, so spending VGPRs to keep the ~60 packed weight
// words register-resident for all 1024 steps is free.
__global__ __launch_bounds__(256, 2) void hrnn_kernel(
    const float* __restrict__ inp,     // (T, B, 1)
    const float* __restrict__ noise1,  // (T, B, N1)
    const float* __restrict__ noise2,  // (T, B, N2)
    const float* __restrict__ W11,     // (N1, N1)
    const float* __restrict__ W22,     // (N2, N2)
    const float* __restrict__ W21,     // (N2, N1)
    const float* __restrict__ W21m,    // (N2, N1)
    const float* __restrict__ Win,     // (N1, 1)
    const float* __restrict__ Wout,    // (1, N2)
    float* __restrict__ out)           // (T, B, 1)
{
  const int lane = threadIdx.x & 63;
  int b = blockIdx.x * 4 + (threadIdx.x >> 6);   // one wave per batch element
  b = __builtin_amdgcn_readfirstlane(b);          // wave-uniform

  // Clamp row index for inactive lanes (their results are never consumed).
  const int i1 = (lane < N1) ? lane : 0;
  const int i2 = (lane < N2) ? lane : 0;

  // Per-lane weight rows packed to f16 pairs (column 2m, 2m+1), loop-invariant
  // across all T steps -> registers. 60 words vs 120 fp32 before.
  unsigned w11p[N1 / 2], w21p[N1 / 2], w22p[N2 / 2];
#pragma unroll
  for (int m = 0; m < N1 / 2; ++m)
    w11p[m] = pack_f16(W11[i1 * N1 + 2 * m], W11[i1 * N1 + 2 * m + 1]);
#pragma unroll
  for (int m = 0; m < N1 / 2; ++m)
    w21p[m] = pack_f16(W21[i2 * N1 + 2 * m] * W21m[i2 * N1 + 2 * m],
                       W21[i2 * N1 + 2 * m + 1] * W21m[i2 * N1 + 2 * m + 1]);
#pragma unroll
  for (int m = 0; m < N2 / 2; ++m)
    w22p[m] = pack_f16(W22[i2 * N2 + 2 * m], W22[i2 * N2 + 2 * m + 1]);
  const float win  = (lane < N1) ? Win[lane]  : 0.0f;
  const float wout = (lane < N2) ? Wout[lane] : 0.0f;  // =0 masks p3 reduce

  // State, packed: even lane 2m holds (s[2m], s[2m+1]) as 2xf16.
  // (odd/garbage lanes are never read by the broadcasts.)
  unsigned s1pk = 0u, s2pk = 0u;   // zero state == f16 zero bits

  // 32-bit element indices (max byte offset 503 MB < 4 GB) bumped by
  // wave-uniform strides: 1 v_add_u32 per pointer per step.
  unsigned n1i = (unsigned)b * N1 + (unsigned)i1;
  unsigned n2i = (unsigned)b * N2 + (unsigned)i2;
  unsigned xi  = (unsigned)b;
  unsigned yi  = (unsigned)b;

  // Software pipeline: preload step 0.
  float x_c  = inp[xi];
  float n1_c = noise1[n1i];
  float n2_c = noise2[n2i];

  for (int t = 0; t < T_STEPS; ++t) {
    // ---- issue next step's loads first (overlap with compute) ----
    const unsigned adv = (t < T_STEPS - 1) ? 1u : 0u;   // clamp last prefetch
    xi  += BATCH * adv;
    n1i += (unsigned)(BATCH * N1) * adv;
    n2i += (unsigned)(BATCH * N2) * adv;
    const float x_n  = inp[xi];
    const float n1_n = noise1[n1i];
    const float n2_n = noise2[n2i];

    // ---- phase 1: r1_new = tanh(W11 @ r1 + Win*x + n1) ----
    // 15 readlane + 15 dot2 (was 30 readlane + 30 fma)
    float a[2];
    a[0] = fmaf(win, x_c, n1_c);
    a[1] = 0.0f;
#pragma unroll
    for (int m = 0; m < N1 / 2; ++m) {
      const unsigned p = lane_bcast_u(s1pk, 2 * m);
      a[m & 1] = dot2(w11p[m], p, a[m & 1]);
    }
    const float s1n = fast_tanh(a[0] + a[1]);
    // pack r1_new: even lane 2m needs (s1n[2m], s1n[2m+1]) -> partner via xor1
    const float s1o = __shfl_xor(s1n, 1, 64);
    const unsigned s1npk = pack_f16(s1n, s1o);

    // ---- phase 2: r2_new = tanh(W22 @ r2 + W21m @ r1_new + n2) ----
    // 45 readlane + 45 dot2 (was 90 readlane + 90 fma).
    // w22 dots first (independent of s1n -> overlap with phase-1 tail).
    float c[4];
    c[0] = n2_c; c[1] = 0.0f; c[2] = 0.0f; c[3] = 0.0f;
#pragma unroll
    for (int m = 0; m < N2 / 2; ++m) {
      const unsigned p = lane_bcast_u(s2pk, 2 * m);
      c[m & 3] = dot2(w22p[m], p, c[m & 3]);
    }
#pragma unroll
    for (int m = 0; m < N1 / 2; ++m) {
      const unsigned p = lane_bcast_u(s1npk, 2 * m);
      c[m & 3] = dot2(w21p[m], p, c[m & 3]);
    }
    const float s2n = fast_tanh((c[0] + c[1]) + (c[2] + c[3]));
    const float s2o = __shfl_xor(s2n, 1, 64);
    const unsigned s2npk = pack_f16(s2n, s2o);

    // ---- phase 3: y = Wout . r2_new  (fp32; wout==0 for lanes >= N2) ----
    float p3 = wout * s2n;
#pragma unroll
    for (int off = 32; off; off >>= 1) p3 += __shfl_xor(p3, off, 64);
    if (lane == 0) out[yi] = p3;
    yi += BATCH;

    // rotate pipeline + state
    s1pk = s1npk; s2pk = s2npk;
    x_c = x_n; n1_c = n1_n; n2_c = n2_n;
  }
}

extern "C" void kernel_launch(void* const* d_in, const int* in_sizes, int n_in,
                              void* d_out, int out_size, void* d_ws, size_t ws_size,
                              hipStream_t stream) {
  const float* inp    = (const float*)d_in[0];
  const float* noise1 = (const float*)d_in[1];
  const float* noise2 = (const float*)d_in[2];
  const float* W11    = (const float*)d_in[3];
  const float* W22    = (const float*)d_in[4];
  const float* W21    = (const float*)d_in[5];
  const float* W21m   = (const float*)d_in[6];
  const float* Win    = (const float*)d_in[7];
  const float* Wout   = (const float*)d_in[8];
  float* out = (float*)d_out;

  dim3 grid(BATCH / 4);   // 512 blocks, 4 waves (4 batch elements) each
  dim3 block(256);
  hipLaunchKernelGGL(hrnn_kernel, grid, block, 0, stream,
                     inp, noise1, noise2, W11, W22, W21, W21m, Win, Wout, out);
}